// Round 6
// baseline (5056.726 us; speedup 1.0000x reference)
//
#include <hip/hip_runtime.h>

constexpr int NN = 500000;
constexpr int NE = 16000000;
constexpr int BN = 256;                    // dst nodes per bucket
constexpr int NBUCK = (NN + BN - 1) / BN;  // 1954
constexpr int NSUB = 8;                    // src slices of 65536 nodes (2 MB of rows)
constexpr int CAP = 1344;                  // per-(bucket,slice): mean 1073, ~8 sigma
constexpr int NB_NODE = (NN + 255) / 256;  // 1954

// ---------------- bucket edges by (dst>>8, src>>16) ----------------
// Slice k's t-rows (64Ki nodes x 32 B = 2 MB) are L2-resident during the
// gather's slice-k sweep.
__global__ void __launch_bounds__(256) bucket_pass(const int* __restrict__ src,
                                                   const int* __restrict__ dst,
                                                   int* __restrict__ bcnt,
                                                   int* __restrict__ bstore) {
    int e0 = (blockIdx.x * 256 + threadIdx.x) * 4;   // NE % 1024 == 0
    int4 s = *(const int4*)(src + e0);
    int4 d = *(const int4*)(dst + e0);
    int sv[4] = {s.x, s.y, s.z, s.w};
    int dv[4] = {d.x, d.y, d.z, d.w};
#pragma unroll
    for (int k = 0; k < 4; ++k) {
        int b = dv[k] >> 8;
        int sub = sv[k] >> 16;               // src slice, 0..7 (NN < 2^19)
        int idx = b * NSUB + sub;
        int pos = atomicAdd(&bcnt[idx], 1);
        if (pos < CAP)
            bstore[(size_t)idx * CAP + pos] = (sv[k] << 8) | (dv[k] & 255);
    }
}

// ---------------- layer-1 pre-transform: x @ Wl1.T (10 -> 5), stride-8 rows ----------------
__global__ void __launch_bounds__(256) transform0(const float* __restrict__ x,
                                                  const float* __restrict__ Wl1,
                                                  float* __restrict__ t) {
    int i = blockIdx.x * 256 + threadIdx.x;
    if (i >= NN) return;
    float xi[10];
#pragma unroll
    for (int k = 0; k < 10; ++k) xi[k] = x[i * 10 + k];
    float v[5];
#pragma unroll
    for (int j = 0; j < 5; ++j) {
        float a = 0.f;
#pragma unroll
        for (int k = 0; k < 10; ++k) a += xi[k] * Wl1[j * 10 + k];
        v[j] = a;
    }
    *(float4*)(t + (size_t)i * 8) = make_float4(v[0], v[1], v[2], v[3]);
    t[(size_t)i * 8 + 4] = v[4];
}

// ---------------- fused edge-parallel gather (LDS accumulate) + node update ----------------
// One block per bucket of 256 dst nodes; edges streamed per src-slice so the
// slice's t-rows stay L2-resident device-wide.
template <int FIN, int FOUT, int FNEXT, bool RELU, bool FIRST, int TSIN>
__global__ void __launch_bounds__(256, 8) bucket_gather(const int* __restrict__ bcnt,
                                                        const int* __restrict__ bstore,
                                                        const float* __restrict__ t,
                                                        const float* __restrict__ hin,
                                                        const float* __restrict__ Wr,
                                                        const float* __restrict__ b,
                                                        const float* __restrict__ Wln,
                                                        float* __restrict__ inv,
                                                        float* __restrict__ hout,
                                                        float* __restrict__ tnext) {
    __shared__ float acc[BN * FOUT];
    __shared__ float scnt[FIRST ? BN : 1];
    const int bkt = blockIdx.x;
    const int tid = threadIdx.x;
    for (int k = tid; k < BN * FOUT; k += 256) acc[k] = 0.f;
    if (FIRST) scnt[tid] = 0.f;
    __syncthreads();

#pragma unroll 1
    for (int sub = 0; sub < NSUB; ++sub) {
        int idx = bkt * NSUB + sub;
        int n = bcnt[idx];
        if (n > CAP) n = CAP;
        const int* bs = bstore + (size_t)idx * CAP;
        int k = tid;
        for (; k + 768 < n; k += 1024) {     // 4 edges in flight per thread
            int e[4] = {bs[k], bs[k + 256], bs[k + 512], bs[k + 768]};
            int dd[4];
            if constexpr (FOUT == 5) {
                float4 p[4]; float q[4];
#pragma unroll
                for (int u = 0; u < 4; ++u) {
                    int sN = e[u] >> 8; dd[u] = e[u] & 255;
                    p[u] = *(const float4*)(t + (size_t)sN * 8);
                    q[u] = t[(size_t)sN * 8 + 4];
                }
#pragma unroll
                for (int u = 0; u < 4; ++u) {
                    float* a = &acc[dd[u] * 5];
                    atomicAdd(a + 0, p[u].x); atomicAdd(a + 1, p[u].y);
                    atomicAdd(a + 2, p[u].z); atomicAdd(a + 3, p[u].w);
                    atomicAdd(a + 4, q[u]);
                    if (FIRST) atomicAdd(&scnt[dd[u]], 1.f);
                }
            } else {
                float q[4];
#pragma unroll
                for (int u = 0; u < 4; ++u) {
                    int sN = e[u] >> 8; dd[u] = e[u] & 255;
                    q[u] = t[(size_t)sN];    // TSIN == 1
                }
#pragma unroll
                for (int u = 0; u < 4; ++u) atomicAdd(&acc[dd[u]], q[u]);
            }
        }
        for (; k < n; k += 256) {            // tail
            int e0 = bs[k];
            int sN = e0 >> 8, d0 = e0 & 255;
            if constexpr (FOUT == 5) {
                float4 p = *(const float4*)(t + (size_t)sN * 8);
                float q = t[(size_t)sN * 8 + 4];
                float* a = &acc[d0 * 5];
                atomicAdd(a + 0, p.x); atomicAdd(a + 1, p.y);
                atomicAdd(a + 2, p.z); atomicAdd(a + 3, p.w);
                atomicAdd(a + 4, q);
                if (FIRST) atomicAdd(&scnt[d0], 1.f);
            } else {
                atomicAdd(&acc[d0], t[(size_t)sN]);
            }
        }
    }
    __syncthreads();

    // ---- node update: one node per thread ----
    int node = bkt * BN + tid;
    if (node >= NN) return;
    float iv;
    if (FIRST) {
        iv = 1.0f / fmaxf(scnt[tid], 1.0f);
        inv[node] = iv;
    } else {
        iv = inv[node];
    }
    float vin[FIN];
#pragma unroll
    for (int k = 0; k < FIN; ++k) vin[k] = hin[(size_t)node * FIN + k];
    float ho[FOUT];
#pragma unroll
    for (int jo = 0; jo < FOUT; ++jo) {
        float v = acc[tid * FOUT + jo] * iv + b[jo];
#pragma unroll
        for (int k = 0; k < FIN; ++k) v += vin[k] * Wr[jo * FIN + k];
        if (RELU) v = fmaxf(v, 0.f);
        hout[(size_t)node * FOUT + jo] = v;
        ho[jo] = v;
    }
    if constexpr (FNEXT == 5) {
        float tv[5];
#pragma unroll
        for (int j2 = 0; j2 < 5; ++j2) {
            float v = 0.f;
#pragma unroll
            for (int jo = 0; jo < FOUT; ++jo) v += ho[jo] * Wln[j2 * FOUT + jo];
            tv[j2] = v;
        }
        *(float4*)(tnext + (size_t)node * 8) = make_float4(tv[0], tv[1], tv[2], tv[3]);
        tnext[(size_t)node * 8 + 4] = tv[4];
    } else if constexpr (FNEXT == 1) {
        float v = 0.f;
#pragma unroll
        for (int jo = 0; jo < FOUT; ++jo) v += ho[jo] * Wln[jo];
        tnext[node] = v;                     // stride-1 plane for the final layer
    }
}

extern "C" void kernel_launch(void* const* d_in, const int* in_sizes, int n_in,
                              void* d_out, int out_size, void* d_ws, size_t ws_size,
                              hipStream_t stream) {
    (void)in_sizes; (void)n_in; (void)out_size; (void)ws_size;
    const float* x    = (const float*)d_in[0];
    const int*   ei   = (const int*)d_in[1];
    const float* Wl1  = (const float*)d_in[2];
    const float* Wr1  = (const float*)d_in[3];
    const float* b1   = (const float*)d_in[4];
    const float* Wlm  = (const float*)d_in[5];
    const float* Wrm  = (const float*)d_in[6];
    const float* bm   = (const float*)d_in[7];
    const float* Wl10 = (const float*)d_in[8];
    const float* Wr10 = (const float*)d_in[9];
    const float* b10  = (const float*)d_in[10];
    float* out = (float*)d_out;

    const int* src = ei;
    const int* dst = ei + NE;

    // workspace layout (4-byte units), ~138 MB
    int* wsI = (int*)d_ws;
    int*   bcnt   = wsI;                        // 1954*8 = 15632 -> pad 16384
    int*   bstore = wsI + 16384;                // 1954*8*1344 = 21,009,408
    float* inv    = (float*)(wsI + 21025792);   // 500,224
    float* tA     = (float*)(wsI + 21526016);   // 8*NN = 4,000,000 (16B aligned)
    float* tB     = (float*)(wsI + 25526016);   // 8*NN
    float* hA     = (float*)(wsI + 29526016);   // 5*NN
    float* hB     = (float*)(wsI + 32026016);   // 5*NN -> end 34,526,016

    dim3 blk(256);
    dim3 nb(NB_NODE);
    dim3 gb(NBUCK);

    // ---- bucket build ----
    hipMemsetAsync(bcnt, 0, 16384 * sizeof(int), stream);
    bucket_pass<<<dim3(NE / 1024), blk, 0, stream>>>(src, dst, bcnt, bstore);

    // ---- layer 1 (10 -> 5); counts degree, writes inv ----
    transform0<<<nb, blk, 0, stream>>>(x, Wl1, tA);
    bucket_gather<10, 5, 5, true, true, 8><<<gb, blk, 0, stream>>>(
        bcnt, bstore, tA, x, Wr1, b1, Wlm, inv, hA, tB);

    // ---- middle layers 0..6 (5 -> 5) ----
    const float* tcur = tB; float* tnxt = tA;
    const float* hcur = hA; float* hnext = hB;
    for (int mi = 0; mi < 7; ++mi) {
        bucket_gather<5, 5, 5, true, false, 8><<<gb, blk, 0, stream>>>(
            bcnt, bstore, tcur, hcur, Wrm + mi * 25, bm + mi * 5,
            Wlm + (mi + 1) * 25, inv, hnext, tnxt);
        const float* tt = tcur; tcur = tnxt; tnxt = (float*)tt;
        const float* th = hcur; hcur = hnext; hnext = (float*)th;
    }
    // ---- middle layer 7: next pre-transform is final (5 -> 1) -> stride-1 plane ----
    bucket_gather<5, 5, 1, true, false, 8><<<gb, blk, 0, stream>>>(
        bcnt, bstore, tcur, hcur, Wrm + 7 * 25, bm + 7 * 5,
        Wl10, inv, hnext, tnxt);
    // ---- final layer (5 -> 1), no relu; slice = 256 KB, trivially resident ----
    bucket_gather<5, 1, 0, false, false, 1><<<gb, blk, 0, stream>>>(
        bcnt, bstore, tnxt, hnext, Wr10, b10, nullptr, inv, out, nullptr);
}

// Round 7
// 3314.815 us; speedup vs baseline: 1.5255x; 1.5255x over previous
//
#include <hip/hip_runtime.h>

constexpr int NN = 500000;
constexpr int NE = 16000000;
constexpr int BN = 1024;                     // dst nodes per bucket
constexpr int NBUCK = (NN + BN - 1) / BN;    // 489
constexpr int CAPA = 34048;                  // per-bucket cap: mean 32768, +7 sigma
constexpr int TILE = 32768;                  // edges per pass-A tile
constexpr int NTILE = (NE + TILE - 1) / TILE; // 489
constexpr int NB_NODE = (NN + 255) / 256;    // 1954

// ---------------- pass A: tile-local counting sort into 489 dst buckets ----------------
// Per tile, each bucket's entries land in one contiguous reserved run (~67
// entries = 268 B) -> near-full-line writes. 489 global atomics per tile.
__global__ void __launch_bounds__(1024) passA(const int* __restrict__ src,
                                              const int* __restrict__ dst,
                                              int* __restrict__ gcnt,
                                              int* __restrict__ storeA) {
    __shared__ int hist[512];
    __shared__ int cur[512];
    const int tid = threadIdx.x;
    const int base = blockIdx.x * TILE;
    const int nt = min(TILE, NE - base);
    if (tid < 512) hist[tid] = 0;
    __syncthreads();
    for (int i = tid; i < nt; i += 1024)
        atomicAdd(&hist[dst[base + i] >> 10], 1);
    __syncthreads();
    if (tid < NBUCK) {
        int c = hist[tid];
        int g = (c > 0) ? atomicAdd(&gcnt[tid], c) : 0;
        cur[tid] = tid * CAPA + g;             // absolute index into storeA
    }
    __syncthreads();
    for (int i = tid; i < nt; i += 1024) {
        int d = dst[base + i];
        int s = src[base + i];                 // tile window is L2-hot on re-read
        int b = d >> 10;
        int p = atomicAdd(&cur[b], 1);
        if (p < (b + 1) * CAPA)                // statistically never fails
            storeA[p] = (s << 10) | (d & 1023);
    }
}

// ---------------- pass B: per-bucket counting sort by dst; emits inv[] ----------------
__global__ void __launch_bounds__(512) passB(const int* __restrict__ gcnt,
                                             const int* __restrict__ storeA,
                                             int* __restrict__ sortedB,
                                             float* __restrict__ inv) {
    __shared__ int hist[BN];
    __shared__ int cur[BN];
    __shared__ int sc[512];
    const int bkt = blockIdx.x;
    const int tid = threadIdx.x;
    hist[tid] = 0; hist[tid + 512] = 0;
    __syncthreads();
    const int n = min(gcnt[bkt], CAPA);
    const int* bs = storeA + (size_t)bkt * CAPA;
    for (int k = tid; k < n; k += 512)
        atomicAdd(&hist[bs[k] & 1023], 1);
    __syncthreads();
    int v0 = hist[2 * tid], v1 = hist[2 * tid + 1];
    int s = v0 + v1;
    sc[tid] = s;
    __syncthreads();
    for (int off = 1; off < 512; off <<= 1) {
        int add = (tid >= off) ? sc[tid - off] : 0;
        __syncthreads();
        sc[tid] += add;
        __syncthreads();
    }
    int excl = sc[tid] - s;
    int gb = bkt * CAPA;
    cur[2 * tid] = gb + excl;
    cur[2 * tid + 1] = gb + excl + v0;
    int node = bkt * BN + 2 * tid;
    if (node < NN) inv[node] = 1.0f / fmaxf((float)v0, 1.0f);
    if (node + 1 < NN) inv[node + 1] = 1.0f / fmaxf((float)v1, 1.0f);
    __syncthreads();
    for (int k = tid; k < n; k += 512) {
        int e = bs[k];
        int p = atomicAdd(&cur[e & 1023], 1);
        sortedB[p] = e;                        // dst-runs ~32 entries = 128 B
    }
}

// ---------------- layer-1 pre-transform: x @ Wl1.T (10 -> 5), stride-8 rows ----------------
__global__ void __launch_bounds__(256) transform0(const float* __restrict__ x,
                                                  const float* __restrict__ Wl1,
                                                  float* __restrict__ t) {
    int i = blockIdx.x * 256 + threadIdx.x;
    if (i >= NN) return;
    float xi[10];
#pragma unroll
    for (int k = 0; k < 10; ++k) xi[k] = x[i * 10 + k];
    float v[5];
#pragma unroll
    for (int j = 0; j < 5; ++j) {
        float a = 0.f;
#pragma unroll
        for (int k = 0; k < 10; ++k) a += xi[k] * Wl1[j * 10 + k];
        v[j] = a;
    }
    *(float4*)(t + (size_t)i * 8) = make_float4(v[0], v[1], v[2], v[3]);
    t[(size_t)i * 8 + 4] = v[4];
}

// ---------------- sorted gather: register accumulation, flush on dst-change ----------------
template <int FIN, int FOUT, int FNEXT, bool RELU>
__global__ void __launch_bounds__(512) sorted_gather(const int* __restrict__ gcnt,
                                                     const int* __restrict__ sorted,
                                                     const float* __restrict__ t,
                                                     const float* __restrict__ hin,
                                                     const float* __restrict__ Wr,
                                                     const float* __restrict__ b,
                                                     const float* __restrict__ Wln,
                                                     const float* __restrict__ inv,
                                                     float* __restrict__ hout,
                                                     float* __restrict__ tnext) {
    __shared__ float acc[BN * FOUT];
    const int bkt = blockIdx.x;
    const int tid = threadIdx.x;
    for (int k = tid; k < BN * FOUT; k += 512) acc[k] = 0.f;
    __syncthreads();
    const int n = min(gcnt[bkt], CAPA);
    const int* bs = sorted + (size_t)bkt * CAPA;
    const int c = (n + 511) >> 9;
    int k = tid * c;
    const int kend = min(k + c, n);
    int cur = -1;
    float a0 = 0, a1 = 0, a2 = 0, a3 = 0, a4 = 0;
    auto flush = [&]() {
        if (cur >= 0) {
            float* p = &acc[cur * FOUT];
            atomicAdd(p + 0, a0);
            if constexpr (FOUT == 5) {
                atomicAdd(p + 1, a1); atomicAdd(p + 2, a2);
                atomicAdd(p + 3, a3); atomicAdd(p + 4, a4);
            }
        }
    };
    if constexpr (FOUT == 5) {
        for (; k + 3 < kend; k += 4) {
            int e0 = __builtin_nontemporal_load(bs + k);
            int e1 = __builtin_nontemporal_load(bs + k + 1);
            int e2 = __builtin_nontemporal_load(bs + k + 2);
            int e3 = __builtin_nontemporal_load(bs + k + 3);
            int s0 = e0 >> 10, s1 = e1 >> 10, s2 = e2 >> 10, s3 = e3 >> 10;
            float4 p0 = *(const float4*)(t + (size_t)s0 * 8);
            float4 p1 = *(const float4*)(t + (size_t)s1 * 8);
            float4 p2 = *(const float4*)(t + (size_t)s2 * 8);
            float4 p3 = *(const float4*)(t + (size_t)s3 * 8);
            float q0 = t[(size_t)s0 * 8 + 4], q1 = t[(size_t)s1 * 8 + 4];
            float q2 = t[(size_t)s2 * 8 + 4], q3 = t[(size_t)s3 * 8 + 4];
            int d;
            d = e0 & 1023; if (d != cur) { flush(); cur = d; a0 = a1 = a2 = a3 = a4 = 0.f; }
            a0 += p0.x; a1 += p0.y; a2 += p0.z; a3 += p0.w; a4 += q0;
            d = e1 & 1023; if (d != cur) { flush(); cur = d; a0 = a1 = a2 = a3 = a4 = 0.f; }
            a0 += p1.x; a1 += p1.y; a2 += p1.z; a3 += p1.w; a4 += q1;
            d = e2 & 1023; if (d != cur) { flush(); cur = d; a0 = a1 = a2 = a3 = a4 = 0.f; }
            a0 += p2.x; a1 += p2.y; a2 += p2.z; a3 += p2.w; a4 += q2;
            d = e3 & 1023; if (d != cur) { flush(); cur = d; a0 = a1 = a2 = a3 = a4 = 0.f; }
            a0 += p3.x; a1 += p3.y; a2 += p3.z; a3 += p3.w; a4 += q3;
        }
        for (; k < kend; ++k) {
            int e0 = bs[k];
            int s0 = e0 >> 10, d = e0 & 1023;
            float4 p0 = *(const float4*)(t + (size_t)s0 * 8);
            float q0 = t[(size_t)s0 * 8 + 4];
            if (d != cur) { flush(); cur = d; a0 = a1 = a2 = a3 = a4 = 0.f; }
            a0 += p0.x; a1 += p0.y; a2 += p0.z; a3 += p0.w; a4 += q0;
        }
    } else {  // FOUT == 1, t is a stride-1 plane
        for (; k + 3 < kend; k += 4) {
            int e0 = __builtin_nontemporal_load(bs + k);
            int e1 = __builtin_nontemporal_load(bs + k + 1);
            int e2 = __builtin_nontemporal_load(bs + k + 2);
            int e3 = __builtin_nontemporal_load(bs + k + 3);
            float q0 = t[e0 >> 10], q1 = t[e1 >> 10];
            float q2 = t[e2 >> 10], q3 = t[e3 >> 10];
            int d;
            d = e0 & 1023; if (d != cur) { flush(); cur = d; a0 = 0.f; } a0 += q0;
            d = e1 & 1023; if (d != cur) { flush(); cur = d; a0 = 0.f; } a0 += q1;
            d = e2 & 1023; if (d != cur) { flush(); cur = d; a0 = 0.f; } a0 += q2;
            d = e3 & 1023; if (d != cur) { flush(); cur = d; a0 = 0.f; } a0 += q3;
        }
        for (; k < kend; ++k) {
            int e0 = bs[k];
            float q0 = t[e0 >> 10];
            int d = e0 & 1023;
            if (d != cur) { flush(); cur = d; a0 = 0.f; }
            a0 += q0;
        }
    }
    flush();
    __syncthreads();

    // ---- node update: 2 nodes per thread ----
#pragma unroll
    for (int r = 0; r < 2; ++r) {
        int local = tid + r * 512;
        int node = bkt * BN + local;
        if (node >= NN) continue;
        float iv = inv[node];
        float vin[FIN];
#pragma unroll
        for (int kk = 0; kk < FIN; ++kk) vin[kk] = hin[(size_t)node * FIN + kk];
        float ho[FOUT];
#pragma unroll
        for (int jo = 0; jo < FOUT; ++jo) {
            float v = acc[local * FOUT + jo] * iv + b[jo];
#pragma unroll
            for (int kk = 0; kk < FIN; ++kk) v += vin[kk] * Wr[jo * FIN + kk];
            if (RELU) v = fmaxf(v, 0.f);
            hout[(size_t)node * FOUT + jo] = v;
            ho[jo] = v;
        }
        if constexpr (FNEXT == 5) {
            float tv[5];
#pragma unroll
            for (int j2 = 0; j2 < 5; ++j2) {
                float v = 0.f;
#pragma unroll
                for (int jo = 0; jo < FOUT; ++jo) v += ho[jo] * Wln[j2 * FOUT + jo];
                tv[j2] = v;
            }
            *(float4*)(tnext + (size_t)node * 8) = make_float4(tv[0], tv[1], tv[2], tv[3]);
            tnext[(size_t)node * 8 + 4] = tv[4];
        } else if constexpr (FNEXT == 1) {
            float v = 0.f;
#pragma unroll
            for (int jo = 0; jo < FOUT; ++jo) v += ho[jo] * Wln[jo];
            tnext[node] = v;                   // stride-1 plane for the final layer
        }
    }
}

extern "C" void kernel_launch(void* const* d_in, const int* in_sizes, int n_in,
                              void* d_out, int out_size, void* d_ws, size_t ws_size,
                              hipStream_t stream) {
    (void)in_sizes; (void)n_in; (void)out_size; (void)ws_size;
    const float* x    = (const float*)d_in[0];
    const int*   ei   = (const int*)d_in[1];
    const float* Wl1  = (const float*)d_in[2];
    const float* Wr1  = (const float*)d_in[3];
    const float* b1   = (const float*)d_in[4];
    const float* Wlm  = (const float*)d_in[5];
    const float* Wrm  = (const float*)d_in[6];
    const float* bm   = (const float*)d_in[7];
    const float* Wl10 = (const float*)d_in[8];
    const float* Wr10 = (const float*)d_in[9];
    const float* b10  = (const float*)d_in[10];
    float* out = (float*)d_out;

    const int* src = ei;
    const int* dst = ei + NE;

    // workspace layout (4-byte units), ~135 MB
    int* wsI = (int*)d_ws;
    int*   gcnt    = wsI;                         // 489 -> pad 1024
    int*   sortedB = wsI + 1024;                  // 489*34048 = 16,649,472
    float* inv     = (float*)(wsI + 16650496);    // 500,224
    int*   storeA  = wsI + 17150720;              // 16,649,472 (dead after passB)
    // feature tables alias the dead storeA region (13M ints < 16.65M):
    float* tA = (float*)(wsI + 17150720);         // 8*NN = 4,000,000 (16B-aligned)
    float* tB = (float*)(wsI + 21150720);         // 8*NN
    float* hA = (float*)(wsI + 25150720);         // 5*NN
    float* hB = (float*)(wsI + 27650720);         // 5*NN -> end 30,150,720

    dim3 gb(NBUCK);

    // ---- build: two-pass dst sort ----
    hipMemsetAsync(gcnt, 0, 1024 * sizeof(int), stream);
    passA<<<dim3(NTILE), dim3(1024), 0, stream>>>(src, dst, gcnt, storeA);
    passB<<<gb, dim3(512), 0, stream>>>(gcnt, storeA, sortedB, inv);

    // ---- layer 1 (10 -> 5) ----  (transform0 overwrites storeA AFTER passB)
    transform0<<<dim3(NB_NODE), dim3(256), 0, stream>>>(x, Wl1, tA);
    sorted_gather<10, 5, 5, true><<<gb, dim3(512), 0, stream>>>(
        gcnt, sortedB, tA, x, Wr1, b1, Wlm, inv, hA, tB);

    // ---- middle layers 0..6 (5 -> 5) ----
    const float* tcur = tB; float* tnxt = tA;
    const float* hcur = hA; float* hnext = hB;
    for (int mi = 0; mi < 7; ++mi) {
        sorted_gather<5, 5, 5, true><<<gb, dim3(512), 0, stream>>>(
            gcnt, sortedB, tcur, hcur, Wrm + mi * 25, bm + mi * 5,
            Wlm + (mi + 1) * 25, inv, hnext, tnxt);
        const float* tt = tcur; tcur = tnxt; tnxt = (float*)tt;
        const float* th = hcur; hcur = hnext; hnext = (float*)th;
    }
    // ---- middle layer 7: next pre-transform is final (5 -> 1) -> stride-1 plane ----
    sorted_gather<5, 5, 1, true><<<gb, dim3(512), 0, stream>>>(
        gcnt, sortedB, tcur, hcur, Wrm + 7 * 25, bm + 7 * 5,
        Wl10, inv, hnext, tnxt);
    // ---- final layer (5 -> 1), no relu; t plane is 2 MB -> L2-resident ----
    sorted_gather<5, 1, 0, false><<<gb, dim3(512), 0, stream>>>(
        gcnt, sortedB, tnxt, hnext, Wr10, b10, nullptr, inv, out, nullptr);
}